// Round 7
// baseline (207.395 us; speedup 1.0000x reference)
//
#include <hip/hip_runtime.h>
#include <hip/hip_bf16.h>
#include <math.h>

// Shapes (fixed by the problem)
#define BB 2
#define TT 2048
#define DD 512
#define HH 8
#define HD 64
#define FF_ 2048
#define M4 4096  // BB*TT
#define NC 32    // chunks of 64 along T

typedef __attribute__((ext_vector_type(8))) __bf16 bf16x8;
typedef __attribute__((ext_vector_type(4))) float floatx4;

__device__ __forceinline__ unsigned short f2bf(float f) {
  unsigned u = __builtin_bit_cast(unsigned, f);
  u += 0x7fffu + ((u >> 16) & 1u);  // RNE
  return (unsigned short)(u >> 16);
}

__device__ __forceinline__ bf16x8 frag16(const unsigned short* p) {
  return __builtin_bit_cast(bf16x8, *(const uint4*)p);
}

__device__ __forceinline__ floatx4 mfma_bf16(bf16x8 a, bf16x8 b, floatx4 c) {
  return __builtin_amdgcn_mfma_f32_16x16x32_bf16(a, b, c, 0, 0, 0);
}

// async global->LDS, 16B per lane; LDS dest = wave-uniform base + lane*16
__device__ __forceinline__ void gl_lds16(const unsigned short* g, unsigned short* l) {
  __builtin_amdgcn_global_load_lds(
      (const __attribute__((address_space(1))) unsigned int*)g,
      (__attribute__((address_space(3))) unsigned int*)l, 16, 0, 0);
}

// ---------------- prep: 6 weight transposes (blocks 0..3071) + LayerNorm1 (blocks 3072..5119)
__global__ __launch_bounds__(256) void prep_kernel(
    const float* __restrict__ wq, const float* __restrict__ wk,
    const float* __restrict__ wv, const float* __restrict__ wo,
    const float* __restrict__ w1, const float* __restrict__ w2,
    unsigned short* __restrict__ wqkvT, unsigned short* __restrict__ woT,
    unsigned short* __restrict__ w1T, unsigned short* __restrict__ w2T,
    const float* __restrict__ x, const float* __restrict__ g1,
    const float* __restrict__ b1, unsigned short* __restrict__ xn) {
  __shared__ float tile[32][33];
  __shared__ float ls[4], lss[4];
  const int bid = blockIdx.x;
  const int tid = threadIdx.x;
  if (bid < 3072) {
    const int tx = tid & 31, ty = tid >> 5;
    const float* src;
    unsigned short* dst;
    int Kd = 512, Nd = 512, tIdx;
    if (bid < 256) { src = wq; dst = wqkvT; tIdx = bid; }
    else if (bid < 512) { src = wk; dst = wqkvT + 512 * 512; tIdx = bid - 256; }
    else if (bid < 768) { src = wv; dst = wqkvT + 2 * 512 * 512; tIdx = bid - 512; }
    else if (bid < 1024) { src = wo; dst = woT; tIdx = bid - 768; }
    else if (bid < 2048) { src = w1; dst = w1T; Nd = 2048; tIdx = bid - 1024; }
    else { src = w2; dst = w2T; Kd = 2048; tIdx = bid - 2048; }
    const int nTilesX = Nd / 32;
    const int n0 = (tIdx % nTilesX) * 32, k0 = (tIdx / nTilesX) * 32;
    for (int i = ty; i < 32; i += 8)
      tile[i][tx] = src[(size_t)(k0 + i) * Nd + n0 + tx];
    __syncthreads();
    for (int i = ty; i < 32; i += 8)
      dst[(size_t)(n0 + i) * Kd + k0 + tx] = f2bf(tile[tx][i]);
  } else {
    const int row = (bid - 3072) * 2 + (tid >> 7);
    const int t = tid & 127;
    float4 v = ((const float4*)(x + (size_t)row * DD))[t];
    float s = v.x + v.y + v.z + v.w;
    float ss = v.x * v.x + v.y * v.y + v.z * v.z + v.w * v.w;
#pragma unroll
    for (int o = 32; o >= 1; o >>= 1) {
      s += __shfl_xor(s, o);
      ss += __shfl_xor(ss, o);
    }
    if ((tid & 63) == 0) { ls[tid >> 6] = s; lss[tid >> 6] = ss; }
    __syncthreads();
    const int wb = (tid >> 7) * 2;
    float S = ls[wb] + ls[wb + 1];
    float SS = lss[wb] + lss[wb + 1];
    float mean = S * (1.f / DD);
    float var = SS * (1.f / DD) - mean * mean;
    float rstd = rsqrtf(var + 1e-5f);
    int cc = t * 4;
    ushort4 o4;
    o4.x = f2bf((v.x - mean) * rstd * g1[cc + 0] + b1[cc + 0]);
    o4.y = f2bf((v.y - mean) * rstd * g1[cc + 1] + b1[cc + 1]);
    o4.z = f2bf((v.z - mean) * rstd * g1[cc + 2] + b1[cc + 2]);
    o4.w = f2bf((v.w - mean) * rstd * g1[cc + 3] + b1[cc + 3]);
    ((ushort4*)(xn + (size_t)row * DD))[t] = o4;
  }
}

// ---------------- LayerNorm (standalone, for ln2)
__global__ __launch_bounds__(128) void ln_kernel(const float* __restrict__ src,
                                                 const float* __restrict__ gg,
                                                 const float* __restrict__ bb,
                                                 unsigned short* __restrict__ dst) {
  const int row = blockIdx.x;
  const int t = threadIdx.x;
  float4 v = ((const float4*)(src + (size_t)row * DD))[t];
  float s = v.x + v.y + v.z + v.w;
  float ss = v.x * v.x + v.y * v.y + v.z * v.z + v.w * v.w;
#pragma unroll
  for (int o = 32; o >= 1; o >>= 1) {
    s += __shfl_xor(s, o);
    ss += __shfl_xor(ss, o);
  }
  __shared__ float ls[2], lss[2];
  if ((t & 63) == 0) { ls[t >> 6] = s; lss[t >> 6] = ss; }
  __syncthreads();
  float S = ls[0] + ls[1];
  float SS = lss[0] + lss[1];
  float mean = S * (1.f / DD);
  float var = SS * (1.f / DD) - mean * mean;
  float rstd = rsqrtf(var + 1e-5f);
  int c = t * 4;
  ushort4 o4;
  o4.x = f2bf((v.x - mean) * rstd * gg[c + 0] + bb[c + 0]);
  o4.y = f2bf((v.y - mean) * rstd * gg[c + 1] + bb[c + 1]);
  o4.z = f2bf((v.z - mean) * rstd * gg[c + 2] + bb[c + 2]);
  o4.w = f2bf((v.w - mean) * rstd * gg[c + 3] + bb[c + 3]);
  ((ushort4*)(dst + (size_t)row * DD))[t] = o4;
}

// ---------------- K-panel bf16 GEMM: C(M,N) = A(M,K) * Bt(N,K)^T
// KU panels of 32 staged per barrier pair; KU=8 drains 64KB per barrier.
// W = min waves/EU hint (matches LDS-limited blocks/CU).
// EPI 0: QKV (elu+1 Q/K, pad-mask K/V, V and K also stored transposed per-head)
// EPI 1: fp32 out = acc + bias[col] + residual[row,col]
// EPI 2: bf16 out = gelu(acc + bias[col])
template <int BM, int BN, int KU, int K, int EPI, int W>
__global__ __launch_bounds__(256, W) void gemm_ku(
    const unsigned short* __restrict__ A, const unsigned short* __restrict__ Bt,
    int N,
    const float* __restrict__ e0, const float* __restrict__ e1,
    float* __restrict__ o0, unsigned short* __restrict__ ob,
    unsigned short* __restrict__ okk, unsigned short* __restrict__ ov,
    unsigned short* __restrict__ okt,
    const unsigned char* __restrict__ msk) {
  constexpr int FM = BM / 32;
  constexpr int FN = BN / 32;
  constexpr int PAN = BM + BN;
  constexpr int NT = PAN / 16;
  __shared__ __align__(16) unsigned short S[KU][PAN * 32];

  const int tid = threadIdx.x;
  const int wid = tid >> 6;
  const int lane = tid & 63;
  const int ln = lane & 15;
  const int quad = lane >> 4;
  const int wm = (wid >> 1) * (BM / 2);
  const int wn = (wid & 1) * (BN / 2);
  const int m0 = blockIdx.x * BM;
  const int n0 = blockIdx.y * BN;
  const int lrow = lane >> 2;
  const int lk = (lane & 3) * 8;

  floatx4 acc[FM][FN];
#pragma unroll
  for (int i = 0; i < FM; ++i)
#pragma unroll
    for (int j = 0; j < FN; ++j) acc[i][j] = (floatx4){0.f, 0.f, 0.f, 0.f};

  for (int k0 = 0; k0 < K; k0 += KU * 32) {
#pragma unroll
    for (int p = 0; p < KU; ++p)
      for (int i = wid; i < NT; i += 4) {
        int r = i * 16 + lrow;
        const unsigned short* g = (r < BM)
            ? A + (size_t)(m0 + r) * K + k0 + p * 32 + lk
            : Bt + (size_t)(n0 + (r - BM)) * K + k0 + p * 32 + lk;
        gl_lds16(g, &S[p][i * 512]);
      }
    __syncthreads();

#pragma unroll
    for (int p = 0; p < KU; ++p) {
      bf16x8 af[FM], bf[FN];
#pragma unroll
      for (int mb = 0; mb < FM; ++mb)
        af[mb] = frag16(&S[p][(wm + mb * 16 + ln) * 32 + quad * 8]);
#pragma unroll
      for (int nb = 0; nb < FN; ++nb)
        bf[nb] = frag16(&S[p][(BM + wn + nb * 16 + ln) * 32 + quad * 8]);
#pragma unroll
      for (int mb = 0; mb < FM; ++mb)
#pragma unroll
        for (int nb = 0; nb < FN; ++nb)
          acc[mb][nb] = mfma_bf16(af[mb], bf[nb], acc[mb][nb]);
    }
    __syncthreads();
  }

#pragma unroll
  for (int mb = 0; mb < FM; ++mb)
#pragma unroll
    for (int nb = 0; nb < FN; ++nb)
#pragma unroll
      for (int r = 0; r < 4; ++r) {
        int row = m0 + wm + mb * 16 + quad * 4 + r;
        int col = n0 + wn + nb * 16 + ln;
        float v = acc[mb][nb][r];
        if constexpr (EPI == 0) {
          int bq = row >> 11, t = row & 2047;
          float padv = msk[(bq << 11) + t] ? 0.f : 1.f;
          if (col < 512) {  // Q = elu(z)+1
            int h = col >> 6, hd = col & 63;
            float q = v > 0.f ? v + 1.f : expf(v);
            ob[(((size_t)(bq * HH + h) * TT + t) << 6) + hd] = f2bf(q);
          } else if (col < 1024) {  // K = (elu(z)+1)*pad, dual layout
            int c2 = col - 512, h = c2 >> 6, hd = c2 & 63;
            float kf = (v > 0.f ? v + 1.f : expf(v)) * padv;
            unsigned short kb16 = f2bf(kf);
            okk[(((size_t)(bq * HH + h) * TT + t) << 6) + hd] = kb16;
            okt[(((size_t)(bq * HH + h) * HD + hd) << 11) + t] = kb16;
          } else {  // V*pad, stored transposed (B,H,HD,T)
            int c2 = col - 1024, h = c2 >> 6, hd = c2 & 63;
            ov[(((size_t)(bq * HH + h) * HD + hd) << 11) + t] = f2bf(v * padv);
          }
        } else if constexpr (EPI == 1) {
          size_t idx = (size_t)row * N + col;
          o0[idx] = v + e0[col] + e1[idx];
        } else {
          float z = v + e0[col];
          float g = 0.5f * z * (1.f + erff(z * 0.70710678118654752f));
          ob[(size_t)row * N + col] = f2bf(g);
        }
      }
}

// ---------------- per-chunk decayed outer-product states (unchanged from R6)
__global__ __launch_bounds__(256) void state_build(
    const unsigned short* __restrict__ Ktg, const unsigned short* __restrict__ Vtg,
    const float* __restrict__ dlg,
    unsigned short* __restrict__ FTf, unsigned short* __restrict__ FTb,
    float* __restrict__ fvec, float* __restrict__ bvec) {
  __shared__ __align__(16) unsigned short T1[64 * 64];
  __shared__ __align__(16) unsigned short T2[64 * 64];
  const int c = blockIdx.x, bh = blockIdx.y, h = bh & 7;
  const int tid = threadIdx.x, wid = tid >> 6, lane = tid & 63;
  const int ln = lane & 15, quad = lane >> 4;
  const float dec = 1.f / (1.f + expf(-dlg[h]));
  const float l2d = log2f(fmaxf(dec, 1e-8f));
  const unsigned short* Kt = Ktg + (size_t)bh * HD * TT + c * 64;
  const unsigned short* Vt = Vtg + (size_t)bh * HD * TT + c * 64;

  float sf[2][8], sb[2][8];
#pragma unroll
  for (int kb = 0; kb < 2; ++kb)
#pragma unroll
    for (int jj = 0; jj < 8; ++jj) {
      float jl = (float)(kb * 32 + quad * 8 + jj);
      sf[kb][jj] = exp2f(l2d * (64.f - jl));
      sb[kb][jj] = exp2f(l2d * (jl + 1.f));
    }

  bf16x8 avf[2], avb[2];
#pragma unroll
  for (int kb = 0; kb < 2; ++kb) {
    bf16x8 raw = frag16(Vt + (size_t)(wid * 16 + ln) * TT + kb * 32 + quad * 8);
#pragma unroll
    for (int jj = 0; jj < 8; ++jj) {
      float v = (float)raw[jj];
      avf[kb][jj] = (__bf16)(v * sf[kb][jj]);
      avb[kb][jj] = (__bf16)(v * sb[kb][jj]);
    }
  }
  bf16x8 bk[2][4];
#pragma unroll
  for (int kb = 0; kb < 2; ++kb)
#pragma unroll
    for (int nb = 0; nb < 4; ++nb)
      bk[kb][nb] = frag16(Kt + (size_t)(nb * 16 + ln) * TT + kb * 32 + quad * 8);

  floatx4 af4[4], ab4[4];
#pragma unroll
  for (int nb = 0; nb < 4; ++nb) { af4[nb] = (floatx4){0,0,0,0}; ab4[nb] = (floatx4){0,0,0,0}; }
#pragma unroll
  for (int kb = 0; kb < 2; ++kb)
#pragma unroll
    for (int nb = 0; nb < 4; ++nb) {
      af4[nb] = mfma_bf16(avf[kb], bk[kb][nb], af4[nb]);
      ab4[nb] = mfma_bf16(avb[kb], bk[kb][nb], ab4[nb]);
    }
#pragma unroll
  for (int nb = 0; nb < 4; ++nb)
#pragma unroll
    for (int r = 0; r < 4; ++r) {
      int mrow = wid * 16 + quad * 4 + r;
      T1[mrow * 64 + nb * 16 + ln] = f2bf(af4[nb][r]);
      T2[mrow * 64 + nb * 16 + ln] = f2bf(ab4[nb][r]);
    }
  if (wid == 0) {
#pragma unroll
    for (int nb = 0; nb < 4; ++nb) {
      float pf = 0.f, pb = 0.f;
#pragma unroll
      for (int kb = 0; kb < 2; ++kb)
#pragma unroll
        for (int jj = 0; jj < 8; ++jj) {
          float kv = (float)bk[kb][nb][jj];
          pf += kv * sf[kb][jj];
          pb += kv * sb[kb][jj];
        }
      pf += __shfl_xor(pf, 16); pf += __shfl_xor(pf, 32);
      pb += __shfl_xor(pb, 16); pb += __shfl_xor(pb, 32);
      if (quad == 0) {
        fvec[((size_t)bh * NC + c) * 64 + nb * 16 + ln] = pf;
        bvec[((size_t)bh * NC + c) * 64 + nb * 16 + ln] = pb;
      }
    }
  }
  __syncthreads();
  size_t ob = ((size_t)bh * NC + c) * 4096 + tid * 16;
  *(uint4*)(FTf + ob) = *(const uint4*)(&T1[tid * 16]);
  *(uint4*)(FTf + ob + 8) = *(const uint4*)(&T1[tid * 16 + 8]);
  *(uint4*)(FTb + ob) = *(const uint4*)(&T2[tid * 16]);
  *(uint4*)(FTb + ob + 8) = *(const uint4*)(&T2[tid * 16 + 8]);
}

// ---------------- combine <=4 chunk states per direction into per-chunk H states
__global__ __launch_bounds__(256) void state_combine(
    const unsigned short* __restrict__ FTf, const unsigned short* __restrict__ FTb,
    const float* __restrict__ fvec, const float* __restrict__ bvec,
    const float* __restrict__ dlg,
    unsigned short* __restrict__ HTf, unsigned short* __restrict__ HTb,
    float* __restrict__ hvf, float* __restrict__ hvb) {
  const int c = blockIdx.x, bh = blockIdx.y, h = bh & 7;
  const int tid = threadIdx.x;
  const float dec = 1.f / (1.f + expf(-dlg[h]));
  const float l2d = log2f(fmaxf(dec, 1e-8f));
  float accf[16], accb[16];
#pragma unroll
  for (int s = 0; s < 16; ++s) { accf[s] = 0.f; accb[s] = 0.f; }
#pragma unroll
  for (int t = 2; t <= 5; ++t) {
    float wf = exp2f(l2d * (float)(64 * (t - 1)));
    float wb = exp2f(l2d * (float)(64 * t - 1));
    if (c - t >= 0) {
      const unsigned short* src = FTf + ((size_t)bh * NC + (c - t)) * 4096 + tid * 16;
      bf16x8 a0 = frag16(src), a1 = frag16(src + 8);
#pragma unroll
      for (int s = 0; s < 8; ++s) { accf[s] += wf * (float)a0[s]; accf[8 + s] += wf * (float)a1[s]; }
    }
    if (c + t < NC) {
      const unsigned short* src = FTb + ((size_t)bh * NC + (c + t)) * 4096 + tid * 16;
      bf16x8 a0 = frag16(src), a1 = frag16(src + 8);
#pragma unroll
      for (int s = 0; s < 8; ++s) { accb[s] += wb * (float)a0[s]; accb[8 + s] += wb * (float)a1[s]; }
    }
  }
  unsigned short of[16], obb[16];
#pragma unroll
  for (int s = 0; s < 16; ++s) { of[s] = f2bf(accf[s]); obb[s] = f2bf(accb[s]); }
  size_t ob = ((size_t)bh * NC + c) * 4096 + tid * 16;
  *(uint4*)(HTf + ob) = *(const uint4*)&of[0];
  *(uint4*)(HTf + ob + 8) = *(const uint4*)&of[8];
  *(uint4*)(HTb + ob) = *(const uint4*)&obb[0];
  *(uint4*)(HTb + ob + 8) = *(const uint4*)&obb[8];
  if (tid < 64) {
    float vf = 0.f, vb = 0.f;
#pragma unroll
    for (int t = 2; t <= 5; ++t) {
      float wf = exp2f(l2d * (float)(64 * (t - 1)));
      float wb = exp2f(l2d * (float)(64 * t - 1));
      if (c - t >= 0) vf += wf * fvec[((size_t)bh * NC + (c - t)) * 64 + tid];
      if (c + t < NC) vb += wb * bvec[((size_t)bh * NC + (c + t)) * 64 + tid];
    }
    hvf[((size_t)bh * NC + c) * 64 + tid] = vf;
    hvb[((size_t)bh * NC + c) * 64 + tid] = vb;
  }
}

// ---------------- attention v3: whole 3-chunk band staged ONCE, 1 barrier/block
__global__ __launch_bounds__(256) void attn_kernel(
    const unsigned short* __restrict__ Qg, const unsigned short* __restrict__ Kg,
    const unsigned short* __restrict__ Vtg, const float* __restrict__ dlg,
    const unsigned short* __restrict__ HTf, const unsigned short* __restrict__ HTb,
    const float* __restrict__ hvf, const float* __restrict__ hvb,
    unsigned short* __restrict__ attn_out) {
  __shared__ __align__(16) unsigned short Ks[192 * 72];   // K band (j,hd), 27.6KB
  __shared__ __align__(16) unsigned short Vts[64 * 200];  // V^T band (hd,j), 25.6KB
  __shared__ __align__(16) unsigned short Ss[64 * 72];    // one S sub-tile, 9.2KB

  const int tid = threadIdx.x;
  const int wid = tid >> 6;
  const int lane = tid & 63;
  const int ln = lane & 15;
  const int quad = lane >> 4;

  const int c = blockIdx.x;
  const int i0 = c * 64;
  const int bh = blockIdx.y;
  const int b = bh >> 3, h = bh & 7;

  const unsigned short* Qb = Qg + (size_t)bh * TT * HD;
  const unsigned short* Kb = Kg + (size_t)bh * TT * HD;
  const unsigned short* Vb = Vtg + (size_t)bh * HD * TT;

  const float dec = 1.f / (1.f + expf(-dlg[h]));
  const float l2d = log2f(fmaxf(dec, 1e-8f));
  const bool fastp = (l2d >= -1.9f);
  const bool useStates = (l2d * 64.f >= -35.f);

  const int jlo = (c > 0) ? (c - 1) * 64 : 0;
  const int jhi = (c < NC - 1) ? (c + 2) * 64 : TT;
  const int nrows = jhi - jlo;  // 128 or 192

  // ---- stage whole band (K rows + V^T cols), then ONE barrier
  {
    const int rr0 = tid >> 2, cs = (tid & 3) * 16;
    for (int rr = rr0; rr < nrows; rr += 64) {
      const unsigned short* src = Kb + (size_t)(jlo + rr) * HD + cs;
      *(uint4*)&Ks[rr * 72 + cs] = *(const uint4*)src;
      *(uint4*)&Ks[rr * 72 + cs + 8] = *(const uint4*)(src + 8);
    }
    const int vrow = tid >> 2;
    for (int cc = (tid & 3) * 8; cc < nrows; cc += 32)
      *(uint4*)&Vts[vrow * 200 + cc] = *(const uint4*)(Vb + (size_t)vrow * TT + jlo + cc);
  }

  bf16x8 qa[2];
#pragma unroll
  for (int kb = 0; kb < 2; ++kb)
    qa[kb] = frag16(Qb + (size_t)(i0 + wid * 16 + ln) * HD + kb * 32 + quad * 8);

  const int il = wid * 16 + quad * 4;
  float rowp[4], rown[4];
#pragma unroll
  for (int r = 0; r < 4; ++r) {
    rowp[r] = exp2f(l2d * (float)(il + r));
    rown[r] = exp2f(-l2d * (float)(il + r));
  }
  float cfp[4], cfn[4];
#pragma unroll
  for (int nb = 0; nb < 4; ++nb) {
    float jl = (float)(nb * 16 + ln);
    cfp[nb] = exp2f(-l2d * jl);
    cfn[nb] = exp2f(l2d * jl);
  }
  const float w64 = exp2f(l2d * 64.f);

  floatx4 oacc[4];
#pragma unroll
  for (int i = 0; i < 4; ++i) oacc[i] = (floatx4){0.f, 0.f, 0.f, 0.f};
  float zdiag[4] = {0.f, 0.f, 0.f, 0.f};

  __syncthreads();  // the ONLY barrier: band visible

  for (int jb = 0; jb < nrows; jb += 64) {
    const int djt = (jlo >> 6) + (jb >> 6) - c;  // -1, 0, +1

#pragma unroll
    for (int nb = 0; nb < 4; ++nb) {
      floatx4 sacc = (floatx4){0.f, 0.f, 0.f, 0.f};
#pragma unroll
      for (int kb = 0; kb < 2; ++kb) {
        bf16x8 bk = frag16(&Ks[(jb + nb * 16 + ln) * 72 + kb * 32 + quad * 8]);
        sacc = mfma_bf16(qa[kb], bk, sacc);
      }
#pragma unroll
      for (int r = 0; r < 4; ++r) {
        float w;
        if (djt < 0)
          w = fastp ? (w64 * rowp[r]) * cfp[nb]
                    : exp2f(l2d * (float)(64 + il + r - (nb * 16 + ln)));
        else if (djt > 0)
          w = fastp ? (w64 * rown[r]) * cfn[nb]
                    : exp2f(l2d * (float)(64 + (nb * 16 + ln) - (il + r)));
        else {
          int sd = il + r - (nb * 16 + ln);
          w = exp2f(l2d * fabsf((float)sd));
        }
        float sv = sacc[r] * w;
        zdiag[r] += sv;
        Ss[(wid * 16 + quad * 4 + r) * 72 + nb * 16 + ln] = f2bf(sv);
      }
    }
    // PV: Ss rows are this wave's own writes (LDS in-order per wave); Vts barrier-covered
    bf16x8 af[2];
#pragma unroll
    for (int kb = 0; kb < 2; ++kb)
      af[kb] = frag16(&Ss[(wid * 16 + ln) * 72 + kb * 32 + quad * 8]);
#pragma unroll
    for (int n2 = 0; n2 < 4; ++n2)
#pragma unroll
      for (int kb = 0; kb < 2; ++kb) {
        bf16x8 bv = frag16(&Vts[(n2 * 16 + ln) * 200 + jb + kb * 32 + quad * 8]);
        oacc[n2] = mfma_bf16(af[kb], bv, oacc[n2]);
      }
  }

  float zstate[4] = {0.f, 0.f, 0.f, 0.f};
  if (useStates) {
    const size_t hb = ((size_t)bh * NC + c) * 4096;
    const size_t vb64 = ((size_t)bh * NC + c) * 64;
    floatx4 pacc[4], qacc[4];
#pragma unroll
    for (int i = 0; i < 4; ++i) { pacc[i] = (floatx4){0,0,0,0}; qacc[i] = (floatx4){0,0,0,0}; }
#pragma unroll
    for (int n2 = 0; n2 < 4; ++n2)
#pragma unroll
      for (int kb = 0; kb < 2; ++kb) {
        bf16x8 hf = frag16(HTf + hb + (size_t)(n2 * 16 + ln) * 64 + kb * 32 + quad * 8);
        bf16x8 hbk = frag16(HTb + hb + (size_t)(n2 * 16 + ln) * 64 + kb * 32 + quad * 8);
        pacc[n2] = mfma_bf16(qa[kb], hf, pacc[n2]);
        qacc[n2] = mfma_bf16(qa[kb], hbk, qacc[n2]);
      }
    float zp = 0.f, zq = 0.f;
#pragma unroll
    for (int kb = 0; kb < 2; ++kb) {
      const float* hvp = hvf + vb64 + kb * 32 + quad * 8;
      const float* hvq = hvb + vb64 + kb * 32 + quad * 8;
#pragma unroll
      for (int jj = 0; jj < 8; ++jj) {
        float qv = (float)qa[kb][jj];
        zp += qv * hvp[jj];
        zq += qv * hvq[jj];
      }
    }
    zp += __shfl_xor(zp, 16); zp += __shfl_xor(zp, 32);
    zq += __shfl_xor(zq, 16); zq += __shfl_xor(zq, 32);
#pragma unroll
    for (int n2 = 0; n2 < 4; ++n2)
#pragma unroll
      for (int r = 0; r < 4; ++r)
        oacc[n2][r] += rowp[r] * pacc[n2][r] + rown[r] * qacc[n2][r];
#pragma unroll
    for (int r = 0; r < 4; ++r)
      zstate[r] = rowp[r] * __shfl(zp, quad * 4 + r) + rown[r] * __shfl(zq, quad * 4 + r);
  }

  float rz[4];
#pragma unroll
  for (int r = 0; r < 4; ++r) {
    float z = zdiag[r];
    z += __shfl_xor(z, 1);
    z += __shfl_xor(z, 2);
    z += __shfl_xor(z, 4);
    z += __shfl_xor(z, 8);
    z += zstate[r];
    rz[r] = 1.f / fmaxf(z, 1e-6f);
  }

#pragma unroll
  for (int n2 = 0; n2 < 4; ++n2)
#pragma unroll
    for (int r = 0; r < 4; ++r) {
      int i = i0 + wid * 16 + quad * 4 + r;
      int col = h * 64 + n2 * 16 + ln;
      attn_out[(size_t)(b * TT + i) * DD + col] = f2bf(oacc[n2][r] * rz[r]);
    }
}

extern "C" void kernel_launch(void* const* d_in, const int* in_sizes, int n_in,
                              void* d_out, int out_size, void* d_ws, size_t ws_size,
                              hipStream_t stream) {
  const float* x = (const float*)d_in[0];
  const unsigned char* msk = (const unsigned char*)d_in[1];
  const float* wq = (const float*)d_in[2];
  const float* wk = (const float*)d_in[3];
  const float* wv = (const float*)d_in[4];
  const float* wo = (const float*)d_in[5];
  const float* bo = (const float*)d_in[6];
  const float* g1 = (const float*)d_in[7];
  const float* b1 = (const float*)d_in[8];
  const float* g2 = (const float*)d_in[9];
  const float* b2 = (const float*)d_in[10];
  const float* w1 = (const float*)d_in[11];
  const float* bf1 = (const float*)d_in[12];
  const float* w2 = (const float*)d_in[13];
  const float* bf2 = (const float*)d_in[14];
  const float* dlg = (const float*)d_in[15];
  float* out = (float*)d_out;

  char* p = (char*)d_ws;
  size_t off = 0;
  auto carve = [&](size_t bytes) {
    char* q = p + off;
    off += (bytes + 255) & ~(size_t)255;
    return q;
  };
  unsigned short* xn = (unsigned short*)carve((size_t)M4 * DD * 2);
  unsigned short* wqkvT = (unsigned short*)carve((size_t)1536 * DD * 2);
  unsigned short* woT = (unsigned short*)carve((size_t)DD * DD * 2);
  unsigned short* w1T = (unsigned short*)carve((size_t)FF_ * DD * 2);
  unsigned short* w2T = (unsigned short*)carve((size_t)DD * FF_ * 2);
  unsigned short* Qb = (unsigned short*)carve((size_t)16 * TT * HD * 2);
  unsigned short* Kb = (unsigned short*)carve((size_t)16 * TT * HD * 2);
  unsigned short* Ktb = (unsigned short*)carve((size_t)16 * HD * TT * 2);
  unsigned short* Vtb = (unsigned short*)carve((size_t)16 * HD * TT * 2);
  unsigned short* attn = (unsigned short*)carve((size_t)M4 * DD * 2);
  float* x2 = (float*)carve((size_t)M4 * DD * 4);
  unsigned short* xn2 = (unsigned short*)carve((size_t)M4 * DD * 2);
  unsigned short* ffh = (unsigned short*)carve((size_t)M4 * FF_ * 2);
  unsigned short* FTfb = (unsigned short*)carve((size_t)16 * NC * 4096 * 2);
  unsigned short* FTbb = (unsigned short*)carve((size_t)16 * NC * 4096 * 2);
  unsigned short* HTfb = (unsigned short*)carve((size_t)16 * NC * 4096 * 2);
  unsigned short* HTbb = (unsigned short*)carve((size_t)16 * NC * 4096 * 2);
  float* fvecb = (float*)carve((size_t)16 * NC * 64 * 4);
  float* bvecb = (float*)carve((size_t)16 * NC * 64 * 4);
  float* hvfb = (float*)carve((size_t)16 * NC * 64 * 4);
  float* hvbb = (float*)carve((size_t)16 * NC * 64 * 4);

  prep_kernel<<<5120, 256, 0, stream>>>(wq, wk, wv, wo, w1, w2,
                                        wqkvT, woT, w1T, w2T, x, g1, b1, xn);

  // QKV: KU=4 (48KB/drain), 4 K-iters, 768 blocks (3/CU)
  gemm_ku<64, 128, 4, 512, 0, 3><<<dim3(M4 / 64, 1536 / 128), 256, 0, stream>>>(
      xn, wqkvT, 1536, nullptr, nullptr, nullptr, Qb, Kb, Vtb, Ktb, msk);

  state_build<<<dim3(NC, 16), 256, 0, stream>>>(Ktb, Vtb, dlg, FTfb, FTbb, fvecb, bvecb);
  state_combine<<<dim3(NC, 16), 256, 0, stream>>>(FTfb, FTbb, fvecb, bvecb, dlg,
                                                  HTfb, HTbb, hvfb, hvbb);
  attn_kernel<<<dim3(NC, 16), 256, 0, stream>>>(Qb, Kb, Vtb, dlg, HTfb, HTbb,
                                                hvfb, hvbb, attn);

  // out-proj: 64x64, KU=8 (64KB/drain), 2 K-iters, 512 blocks
  gemm_ku<64, 64, 8, 512, 1, 2><<<dim3(M4 / 64, DD / 64), 256, 0, stream>>>(
      attn, woT, DD, bo, x, x2, nullptr, nullptr, nullptr, nullptr, nullptr);

  ln_kernel<<<M4, 128, 0, stream>>>(x2, g2, b2, xn2);

  // FFN1: KU=4, 4 K-iters, 1024 blocks
  gemm_ku<64, 128, 4, 512, 2, 3><<<dim3(M4 / 64, FF_ / 128), 256, 0, stream>>>(
      xn2, w1T, FF_, bf1, nullptr, nullptr, ffh, nullptr, nullptr, nullptr, nullptr);

  // FFN2: 64x64, KU=8, 8 K-iters, 512 blocks
  gemm_ku<64, 64, 8, 2048, 1, 2><<<dim3(M4 / 64, DD / 64), 256, 0, stream>>>(
      ffh, w2T, DD, bf2, x2, out, nullptr, nullptr, nullptr, nullptr, nullptr);
}

// Round 8
// 204.742 us; speedup vs baseline: 1.0130x; 1.0130x over previous
//
#include <hip/hip_runtime.h>
#include <hip/hip_bf16.h>
#include <math.h>

// Shapes (fixed by the problem)
#define BB 2
#define TT 2048
#define DD 512
#define HH 8
#define HD 64
#define FF_ 2048
#define M4 4096  // BB*TT
#define NC 32    // chunks of 64 along T

typedef __attribute__((ext_vector_type(8))) __bf16 bf16x8;
typedef __attribute__((ext_vector_type(4))) float floatx4;

__device__ __forceinline__ unsigned short f2bf(float f) {
  unsigned u = __builtin_bit_cast(unsigned, f);
  u += 0x7fffu + ((u >> 16) & 1u);  // RNE
  return (unsigned short)(u >> 16);
}

__device__ __forceinline__ bf16x8 frag16(const unsigned short* p) {
  return __builtin_bit_cast(bf16x8, *(const uint4*)p);
}

__device__ __forceinline__ floatx4 mfma_bf16(bf16x8 a, bf16x8 b, floatx4 c) {
  return __builtin_amdgcn_mfma_f32_16x16x32_bf16(a, b, c, 0, 0, 0);
}

// async global->LDS, 16B per lane; LDS dest = wave-uniform base + lane*16
__device__ __forceinline__ void gl_lds16(const unsigned short* g, unsigned short* l) {
  __builtin_amdgcn_global_load_lds(
      (const __attribute__((address_space(1))) unsigned int*)g,
      (__attribute__((address_space(3))) unsigned int*)l, 16, 0, 0);
}

// ---------------- prep: 6 weight transposes (blocks 0..3071) + LayerNorm1 (blocks 3072..5119)
__global__ __launch_bounds__(256) void prep_kernel(
    const float* __restrict__ wq, const float* __restrict__ wk,
    const float* __restrict__ wv, const float* __restrict__ wo,
    const float* __restrict__ w1, const float* __restrict__ w2,
    unsigned short* __restrict__ wqkvT, unsigned short* __restrict__ woT,
    unsigned short* __restrict__ w1T, unsigned short* __restrict__ w2T,
    const float* __restrict__ x, const float* __restrict__ g1,
    const float* __restrict__ b1, unsigned short* __restrict__ xn) {
  __shared__ float tile[32][33];
  __shared__ float ls[4], lss[4];
  const int bid = blockIdx.x;
  const int tid = threadIdx.x;
  if (bid < 3072) {
    const int tx = tid & 31, ty = tid >> 5;
    const float* src;
    unsigned short* dst;
    int Kd = 512, Nd = 512, tIdx;
    if (bid < 256) { src = wq; dst = wqkvT; tIdx = bid; }
    else if (bid < 512) { src = wk; dst = wqkvT + 512 * 512; tIdx = bid - 256; }
    else if (bid < 768) { src = wv; dst = wqkvT + 2 * 512 * 512; tIdx = bid - 512; }
    else if (bid < 1024) { src = wo; dst = woT; tIdx = bid - 768; }
    else if (bid < 2048) { src = w1; dst = w1T; Nd = 2048; tIdx = bid - 1024; }
    else { src = w2; dst = w2T; Kd = 2048; tIdx = bid - 2048; }
    const int nTilesX = Nd / 32;
    const int n0 = (tIdx % nTilesX) * 32, k0 = (tIdx / nTilesX) * 32;
    for (int i = ty; i < 32; i += 8)
      tile[i][tx] = src[(size_t)(k0 + i) * Nd + n0 + tx];
    __syncthreads();
    for (int i = ty; i < 32; i += 8)
      dst[(size_t)(n0 + i) * Kd + k0 + tx] = f2bf(tile[tx][i]);
  } else {
    const int row = (bid - 3072) * 2 + (tid >> 7);
    const int t = tid & 127;
    float4 v = ((const float4*)(x + (size_t)row * DD))[t];
    float s = v.x + v.y + v.z + v.w;
    float ss = v.x * v.x + v.y * v.y + v.z * v.z + v.w * v.w;
#pragma unroll
    for (int o = 32; o >= 1; o >>= 1) {
      s += __shfl_xor(s, o);
      ss += __shfl_xor(ss, o);
    }
    if ((tid & 63) == 0) { ls[tid >> 6] = s; lss[tid >> 6] = ss; }
    __syncthreads();
    const int wb = (tid >> 7) * 2;
    float S = ls[wb] + ls[wb + 1];
    float SS = lss[wb] + lss[wb + 1];
    float mean = S * (1.f / DD);
    float var = SS * (1.f / DD) - mean * mean;
    float rstd = rsqrtf(var + 1e-5f);
    int cc = t * 4;
    ushort4 o4;
    o4.x = f2bf((v.x - mean) * rstd * g1[cc + 0] + b1[cc + 0]);
    o4.y = f2bf((v.y - mean) * rstd * g1[cc + 1] + b1[cc + 1]);
    o4.z = f2bf((v.z - mean) * rstd * g1[cc + 2] + b1[cc + 2]);
    o4.w = f2bf((v.w - mean) * rstd * g1[cc + 3] + b1[cc + 3]);
    ((ushort4*)(xn + (size_t)row * DD))[t] = o4;
  }
}

// ---------------- LayerNorm (standalone, for ln2)
__global__ __launch_bounds__(128) void ln_kernel(const float* __restrict__ src,
                                                 const float* __restrict__ gg,
                                                 const float* __restrict__ bb,
                                                 unsigned short* __restrict__ dst) {
  const int row = blockIdx.x;
  const int t = threadIdx.x;
  float4 v = ((const float4*)(src + (size_t)row * DD))[t];
  float s = v.x + v.y + v.z + v.w;
  float ss = v.x * v.x + v.y * v.y + v.z * v.z + v.w * v.w;
#pragma unroll
  for (int o = 32; o >= 1; o >>= 1) {
    s += __shfl_xor(s, o);
    ss += __shfl_xor(ss, o);
  }
  __shared__ float ls[2], lss[2];
  if ((t & 63) == 0) { ls[t >> 6] = s; lss[t >> 6] = ss; }
  __syncthreads();
  float S = ls[0] + ls[1];
  float SS = lss[0] + lss[1];
  float mean = S * (1.f / DD);
  float var = SS * (1.f / DD) - mean * mean;
  float rstd = rsqrtf(var + 1e-5f);
  int c = t * 4;
  ushort4 o4;
  o4.x = f2bf((v.x - mean) * rstd * gg[c + 0] + bb[c + 0]);
  o4.y = f2bf((v.y - mean) * rstd * gg[c + 1] + bb[c + 1]);
  o4.z = f2bf((v.z - mean) * rstd * gg[c + 2] + bb[c + 2]);
  o4.w = f2bf((v.w - mean) * rstd * gg[c + 3] + bb[c + 3]);
  ((ushort4*)(dst + (size_t)row * DD))[t] = o4;
}

// ---------------- K-panel bf16 GEMM: C(M,N) = A(M,K) * Bt(N,K)^T
// KU panels of 32 staged per barrier pair (global_load_lds 16B, 64B-row LDS).
// EPI 0: QKV. Q: elu+1, row-major direct. K: elu+1 * pad, row-major direct +
//        TRANSPOSED copy via LDS scatter->coalesced stores. V: pad, transposed
//        via LDS only. (global 2B scatters eliminated — that was the R6 cost)
// EPI 1: fp32 out = acc + bias[col] + residual[row,col]
// EPI 2: bf16 out = gelu(acc + bias[col])
template <int BM, int BN, int KU, int K, int EPI, int W>
__global__ __launch_bounds__(256, W) void gemm_ku(
    const unsigned short* __restrict__ A, const unsigned short* __restrict__ Bt,
    int N,
    const float* __restrict__ e0, const float* __restrict__ e1,
    float* __restrict__ o0, unsigned short* __restrict__ ob,
    unsigned short* __restrict__ okk, unsigned short* __restrict__ ov,
    unsigned short* __restrict__ okt,
    const unsigned char* __restrict__ msk) {
  constexpr int FM = BM / 32;
  constexpr int FN = BN / 32;
  constexpr int PAN = BM + BN;
  constexpr int NT = PAN / 16;
  __shared__ __align__(16) unsigned short S[KU][PAN * 32];

  const int tid = threadIdx.x;
  const int wid = tid >> 6;
  const int lane = tid & 63;
  const int ln = lane & 15;
  const int quad = lane >> 4;
  const int wm = (wid >> 1) * (BM / 2);
  const int wn = (wid & 1) * (BN / 2);
  const int m0 = blockIdx.x * BM;
  const int n0 = blockIdx.y * BN;
  const int lrow = lane >> 2;
  const int lk = (lane & 3) * 8;

  floatx4 acc[FM][FN];
#pragma unroll
  for (int i = 0; i < FM; ++i)
#pragma unroll
    for (int j = 0; j < FN; ++j) acc[i][j] = (floatx4){0.f, 0.f, 0.f, 0.f};

  for (int k0 = 0; k0 < K; k0 += KU * 32) {
#pragma unroll
    for (int p = 0; p < KU; ++p)
      for (int i = wid; i < NT; i += 4) {
        int r = i * 16 + lrow;
        const unsigned short* g = (r < BM)
            ? A + (size_t)(m0 + r) * K + k0 + p * 32 + lk
            : Bt + (size_t)(n0 + (r - BM)) * K + k0 + p * 32 + lk;
        gl_lds16(g, &S[p][i * 512]);
      }
    __syncthreads();

#pragma unroll
    for (int p = 0; p < KU; ++p) {
      bf16x8 af[FM], bf[FN];
#pragma unroll
      for (int mb = 0; mb < FM; ++mb)
        af[mb] = frag16(&S[p][(wm + mb * 16 + ln) * 32 + quad * 8]);
#pragma unroll
      for (int nb = 0; nb < FN; ++nb)
        bf[nb] = frag16(&S[p][(BM + wn + nb * 16 + ln) * 32 + quad * 8]);
#pragma unroll
      for (int mb = 0; mb < FM; ++mb)
#pragma unroll
        for (int nb = 0; nb < FN; ++nb)
          acc[mb][nb] = mfma_bf16(af[mb], bf[nb], acc[mb][nb]);
    }
    __syncthreads();
  }

  if constexpr (EPI == 0) {
    // block-uniform quadrant (BN=128 divides the 512-col quadrants)
    const bool isQ = (n0 < 512);
    const bool isK = (n0 >= 512 && n0 < 1024);
    const int bq = m0 >> 11;          // batch (64-row tile stays within one b)
    const int t0 = m0 & 2047;         // chunk start within T
    unsigned short* St = (unsigned short*)S;  // 128x72 transposed tile (18.4KB)
#pragma unroll
    for (int mb = 0; mb < FM; ++mb)
#pragma unroll
      for (int nb = 0; nb < FN; ++nb)
#pragma unroll
        for (int r = 0; r < 4; ++r) {
          int rloc = wm + mb * 16 + quad * 4 + r;   // 0..63 (t offset)
          int cloc = wn + nb * 16 + ln;             // 0..127
          int row = m0 + rloc, t = row & 2047;
          float v = acc[mb][nb][r];
          float padv = msk[(bq << 11) + t] ? 0.f : 1.f;
          if (isQ) {
            int col = n0 + cloc, h = col >> 6, hd = col & 63;
            float q = v > 0.f ? v + 1.f : expf(v);
            ob[(((size_t)(bq * HH + h) * TT + t) << 6) + hd] = f2bf(q);
          } else if (isK) {
            int c2 = n0 - 512 + cloc, h = c2 >> 6, hd = c2 & 63;
            float kf = (v > 0.f ? v + 1.f : expf(v)) * padv;
            unsigned short kb16 = f2bf(kf);
            okk[(((size_t)(bq * HH + h) * TT + t) << 6) + hd] = kb16;
            St[cloc * 72 + rloc] = kb16;  // LDS scatter (cheap)
          } else {
            St[cloc * 72 + rloc] = f2bf(v * padv);
          }
        }
    if (!isQ) {
      __syncthreads();
      // coalesced transposed store: thread -> (col c2=tid>>1, half tid&1), 64B each
      const int cloc = tid >> 1, half = tid & 1;
      const int cg = (n0 - (isK ? 512 : 1024)) + cloc;
      const int h = cg >> 6, hd = cg & 63;
      unsigned short* dst = (isK ? okt : ov) +
          (((size_t)(bq * HH + h) * HD + hd) << 11) + t0 + half * 32;
      const unsigned short* srcl = &St[cloc * 72 + half * 32];
      *(uint4*)(dst) = *(const uint4*)(srcl);
      *(uint4*)(dst + 8) = *(const uint4*)(srcl + 8);
      *(uint4*)(dst + 16) = *(const uint4*)(srcl + 16);
      *(uint4*)(dst + 24) = *(const uint4*)(srcl + 24);
    }
  } else {
#pragma unroll
    for (int mb = 0; mb < FM; ++mb)
#pragma unroll
      for (int nb = 0; nb < FN; ++nb)
#pragma unroll
        for (int r = 0; r < 4; ++r) {
          int row = m0 + wm + mb * 16 + quad * 4 + r;
          int col = n0 + wn + nb * 16 + ln;
          float v = acc[mb][nb][r];
          if constexpr (EPI == 1) {
            size_t idx = (size_t)row * N + col;
            o0[idx] = v + e0[col] + e1[idx];
          } else {
            float z = v + e0[col];
            float g = 0.5f * z * (1.f + erff(z * 0.70710678118654752f));
            ob[(size_t)row * N + col] = f2bf(g);
          }
        }
  }
}

// ---------------- per-chunk decayed outer-product states
__global__ __launch_bounds__(256) void state_build(
    const unsigned short* __restrict__ Ktg, const unsigned short* __restrict__ Vtg,
    const float* __restrict__ dlg,
    unsigned short* __restrict__ FTf, unsigned short* __restrict__ FTb,
    float* __restrict__ fvec, float* __restrict__ bvec) {
  __shared__ __align__(16) unsigned short T1[64 * 64];
  __shared__ __align__(16) unsigned short T2[64 * 64];
  const int c = blockIdx.x, bh = blockIdx.y, h = bh & 7;
  const int tid = threadIdx.x, wid = tid >> 6, lane = tid & 63;
  const int ln = lane & 15, quad = lane >> 4;
  const float dec = 1.f / (1.f + expf(-dlg[h]));
  const float l2d = log2f(fmaxf(dec, 1e-8f));
  const unsigned short* Kt = Ktg + (size_t)bh * HD * TT + c * 64;
  const unsigned short* Vt = Vtg + (size_t)bh * HD * TT + c * 64;

  float sf[2][8], sb[2][8];
#pragma unroll
  for (int kb = 0; kb < 2; ++kb)
#pragma unroll
    for (int jj = 0; jj < 8; ++jj) {
      float jl = (float)(kb * 32 + quad * 8 + jj);
      sf[kb][jj] = exp2f(l2d * (64.f - jl));
      sb[kb][jj] = exp2f(l2d * (jl + 1.f));
    }

  bf16x8 avf[2], avb[2];
#pragma unroll
  for (int kb = 0; kb < 2; ++kb) {
    bf16x8 raw = frag16(Vt + (size_t)(wid * 16 + ln) * TT + kb * 32 + quad * 8);
#pragma unroll
    for (int jj = 0; jj < 8; ++jj) {
      float v = (float)raw[jj];
      avf[kb][jj] = (__bf16)(v * sf[kb][jj]);
      avb[kb][jj] = (__bf16)(v * sb[kb][jj]);
    }
  }
  bf16x8 bk[2][4];
#pragma unroll
  for (int kb = 0; kb < 2; ++kb)
#pragma unroll
    for (int nb = 0; nb < 4; ++nb)
      bk[kb][nb] = frag16(Kt + (size_t)(nb * 16 + ln) * TT + kb * 32 + quad * 8);

  floatx4 af4[4], ab4[4];
#pragma unroll
  for (int nb = 0; nb < 4; ++nb) { af4[nb] = (floatx4){0,0,0,0}; ab4[nb] = (floatx4){0,0,0,0}; }
#pragma unroll
  for (int kb = 0; kb < 2; ++kb)
#pragma unroll
    for (int nb = 0; nb < 4; ++nb) {
      af4[nb] = mfma_bf16(avf[kb], bk[kb][nb], af4[nb]);
      ab4[nb] = mfma_bf16(avb[kb], bk[kb][nb], ab4[nb]);
    }
#pragma unroll
  for (int nb = 0; nb < 4; ++nb)
#pragma unroll
    for (int r = 0; r < 4; ++r) {
      int mrow = wid * 16 + quad * 4 + r;
      T1[mrow * 64 + nb * 16 + ln] = f2bf(af4[nb][r]);
      T2[mrow * 64 + nb * 16 + ln] = f2bf(ab4[nb][r]);
    }
  if (wid == 0) {
#pragma unroll
    for (int nb = 0; nb < 4; ++nb) {
      float pf = 0.f, pb = 0.f;
#pragma unroll
      for (int kb = 0; kb < 2; ++kb)
#pragma unroll
        for (int jj = 0; jj < 8; ++jj) {
          float kv = (float)bk[kb][nb][jj];
          pf += kv * sf[kb][jj];
          pb += kv * sb[kb][jj];
        }
      pf += __shfl_xor(pf, 16); pf += __shfl_xor(pf, 32);
      pb += __shfl_xor(pb, 16); pb += __shfl_xor(pb, 32);
      if (quad == 0) {
        fvec[((size_t)bh * NC + c) * 64 + nb * 16 + ln] = pf;
        bvec[((size_t)bh * NC + c) * 64 + nb * 16 + ln] = pb;
      }
    }
  }
  __syncthreads();
  size_t ob = ((size_t)bh * NC + c) * 4096 + tid * 16;
  *(uint4*)(FTf + ob) = *(const uint4*)(&T1[tid * 16]);
  *(uint4*)(FTf + ob + 8) = *(const uint4*)(&T1[tid * 16 + 8]);
  *(uint4*)(FTb + ob) = *(const uint4*)(&T2[tid * 16]);
  *(uint4*)(FTb + ob + 8) = *(const uint4*)(&T2[tid * 16 + 8]);
}

// ---------------- combine <=4 chunk states per direction into per-chunk H states
__global__ __launch_bounds__(256) void state_combine(
    const unsigned short* __restrict__ FTf, const unsigned short* __restrict__ FTb,
    const float* __restrict__ fvec, const float* __restrict__ bvec,
    const float* __restrict__ dlg,
    unsigned short* __restrict__ HTf, unsigned short* __restrict__ HTb,
    float* __restrict__ hvf, float* __restrict__ hvb) {
  const int c = blockIdx.x, bh = blockIdx.y, h = bh & 7;
  const int tid = threadIdx.x;
  const float dec = 1.f / (1.f + expf(-dlg[h]));
  const float l2d = log2f(fmaxf(dec, 1e-8f));
  float accf[16], accb[16];
#pragma unroll
  for (int s = 0; s < 16; ++s) { accf[s] = 0.f; accb[s] = 0.f; }
#pragma unroll
  for (int t = 2; t <= 5; ++t) {
    float wf = exp2f(l2d * (float)(64 * (t - 1)));
    float wb = exp2f(l2d * (float)(64 * t - 1));
    if (c - t >= 0) {
      const unsigned short* src = FTf + ((size_t)bh * NC + (c - t)) * 4096 + tid * 16;
      bf16x8 a0 = frag16(src), a1 = frag16(src + 8);
#pragma unroll
      for (int s = 0; s < 8; ++s) { accf[s] += wf * (float)a0[s]; accf[8 + s] += wf * (float)a1[s]; }
    }
    if (c + t < NC) {
      const unsigned short* src = FTb + ((size_t)bh * NC + (c + t)) * 4096 + tid * 16;
      bf16x8 a0 = frag16(src), a1 = frag16(src + 8);
#pragma unroll
      for (int s = 0; s < 8; ++s) { accb[s] += wb * (float)a0[s]; accb[8 + s] += wb * (float)a1[s]; }
    }
  }
  unsigned short of[16], obb[16];
#pragma unroll
  for (int s = 0; s < 16; ++s) { of[s] = f2bf(accf[s]); obb[s] = f2bf(accb[s]); }
  size_t ob = ((size_t)bh * NC + c) * 4096 + tid * 16;
  *(uint4*)(HTf + ob) = *(const uint4*)&of[0];
  *(uint4*)(HTf + ob + 8) = *(const uint4*)&of[8];
  *(uint4*)(HTb + ob) = *(const uint4*)&obb[0];
  *(uint4*)(HTb + ob + 8) = *(const uint4*)&obb[8];
  if (tid < 64) {
    float vf = 0.f, vb = 0.f;
#pragma unroll
    for (int t = 2; t <= 5; ++t) {
      float wf = exp2f(l2d * (float)(64 * (t - 1)));
      float wb = exp2f(l2d * (float)(64 * t - 1));
      if (c - t >= 0) vf += wf * fvec[((size_t)bh * NC + (c - t)) * 64 + tid];
      if (c + t < NC) vb += wb * bvec[((size_t)bh * NC + (c + t)) * 64 + tid];
    }
    hvf[((size_t)bh * NC + c) * 64 + tid] = vf;
    hvb[((size_t)bh * NC + c) * 64 + tid] = vb;
  }
}

// ---------------- attention v3: whole 3-chunk band staged ONCE, 1 barrier/block
__global__ __launch_bounds__(256) void attn_kernel(
    const unsigned short* __restrict__ Qg, const unsigned short* __restrict__ Kg,
    const unsigned short* __restrict__ Vtg, const float* __restrict__ dlg,
    const unsigned short* __restrict__ HTf, const unsigned short* __restrict__ HTb,
    const float* __restrict__ hvf, const float* __restrict__ hvb,
    unsigned short* __restrict__ attn_out) {
  __shared__ __align__(16) unsigned short Ks[192 * 72];
  __shared__ __align__(16) unsigned short Vts[64 * 200];
  __shared__ __align__(16) unsigned short Ss[64 * 72];

  const int tid = threadIdx.x;
  const int wid = tid >> 6;
  const int lane = tid & 63;
  const int ln = lane & 15;
  const int quad = lane >> 4;

  const int c = blockIdx.x;
  const int i0 = c * 64;
  const int bh = blockIdx.y;
  const int b = bh >> 3, h = bh & 7;

  const unsigned short* Qb = Qg + (size_t)bh * TT * HD;
  const unsigned short* Kb = Kg + (size_t)bh * TT * HD;
  const unsigned short* Vb = Vtg + (size_t)bh * HD * TT;

  const float dec = 1.f / (1.f + expf(-dlg[h]));
  const float l2d = log2f(fmaxf(dec, 1e-8f));
  const bool fastp = (l2d >= -1.9f);
  const bool useStates = (l2d * 64.f >= -35.f);

  const int jlo = (c > 0) ? (c - 1) * 64 : 0;
  const int jhi = (c < NC - 1) ? (c + 2) * 64 : TT;
  const int nrows = jhi - jlo;

  {
    const int rr0 = tid >> 2, cs = (tid & 3) * 16;
    for (int rr = rr0; rr < nrows; rr += 64) {
      const unsigned short* src = Kb + (size_t)(jlo + rr) * HD + cs;
      *(uint4*)&Ks[rr * 72 + cs] = *(const uint4*)src;
      *(uint4*)&Ks[rr * 72 + cs + 8] = *(const uint4*)(src + 8);
    }
    const int vrow = tid >> 2;
    for (int cc = (tid & 3) * 8; cc < nrows; cc += 32)
      *(uint4*)&Vts[vrow * 200 + cc] = *(const uint4*)(Vb + (size_t)vrow * TT + jlo + cc);
  }

  bf16x8 qa[2];
#pragma unroll
  for (int kb = 0; kb < 2; ++kb)
    qa[kb] = frag16(Qb + (size_t)(i0 + wid * 16 + ln) * HD + kb * 32 + quad * 8);

  const int il = wid * 16 + quad * 4;
  float rowp[4], rown[4];
#pragma unroll
  for (int r = 0; r < 4; ++r) {
    rowp[r] = exp2f(l2d * (float)(il + r));
    rown[r] = exp2f(-l2d * (float)(il + r));
  }
  float cfp[4], cfn[4];
#pragma unroll
  for (int nb = 0; nb < 4; ++nb) {
    float jl = (float)(nb * 16 + ln);
    cfp[nb] = exp2f(-l2d * jl);
    cfn[nb] = exp2f(l2d * jl);
  }
  const float w64 = exp2f(l2d * 64.f);

  floatx4 oacc[4];
#pragma unroll
  for (int i = 0; i < 4; ++i) oacc[i] = (floatx4){0.f, 0.f, 0.f, 0.f};
  float zdiag[4] = {0.f, 0.f, 0.f, 0.f};

  __syncthreads();

  for (int jb = 0; jb < nrows; jb += 64) {
    const int djt = (jlo >> 6) + (jb >> 6) - c;

#pragma unroll
    for (int nb = 0; nb < 4; ++nb) {
      floatx4 sacc = (floatx4){0.f, 0.f, 0.f, 0.f};
#pragma unroll
      for (int kb = 0; kb < 2; ++kb) {
        bf16x8 bk = frag16(&Ks[(jb + nb * 16 + ln) * 72 + kb * 32 + quad * 8]);
        sacc = mfma_bf16(qa[kb], bk, sacc);
      }
#pragma unroll
      for (int r = 0; r < 4; ++r) {
        float w;
        if (djt < 0)
          w = fastp ? (w64 * rowp[r]) * cfp[nb]
                    : exp2f(l2d * (float)(64 + il + r - (nb * 16 + ln)));
        else if (djt > 0)
          w = fastp ? (w64 * rown[r]) * cfn[nb]
                    : exp2f(l2d * (float)(64 + (nb * 16 + ln) - (il + r)));
        else {
          int sd = il + r - (nb * 16 + ln);
          w = exp2f(l2d * fabsf((float)sd));
        }
        float sv = sacc[r] * w;
        zdiag[r] += sv;
        Ss[(wid * 16 + quad * 4 + r) * 72 + nb * 16 + ln] = f2bf(sv);
      }
    }
    bf16x8 af[2];
#pragma unroll
    for (int kb = 0; kb < 2; ++kb)
      af[kb] = frag16(&Ss[(wid * 16 + ln) * 72 + kb * 32 + quad * 8]);
#pragma unroll
    for (int n2 = 0; n2 < 4; ++n2)
#pragma unroll
      for (int kb = 0; kb < 2; ++kb) {
        bf16x8 bv = frag16(&Vts[(n2 * 16 + ln) * 200 + jb + kb * 32 + quad * 8]);
        oacc[n2] = mfma_bf16(af[kb], bv, oacc[n2]);
      }
  }

  float zstate[4] = {0.f, 0.f, 0.f, 0.f};
  if (useStates) {
    const size_t hb = ((size_t)bh * NC + c) * 4096;
    const size_t vb64 = ((size_t)bh * NC + c) * 64;
    floatx4 pacc[4], qacc[4];
#pragma unroll
    for (int i = 0; i < 4; ++i) { pacc[i] = (floatx4){0,0,0,0}; qacc[i] = (floatx4){0,0,0,0}; }
#pragma unroll
    for (int n2 = 0; n2 < 4; ++n2)
#pragma unroll
      for (int kb = 0; kb < 2; ++kb) {
        bf16x8 hf = frag16(HTf + hb + (size_t)(n2 * 16 + ln) * 64 + kb * 32 + quad * 8);
        bf16x8 hbk = frag16(HTb + hb + (size_t)(n2 * 16 + ln) * 64 + kb * 32 + quad * 8);
        pacc[n2] = mfma_bf16(qa[kb], hf, pacc[n2]);
        qacc[n2] = mfma_bf16(qa[kb], hbk, qacc[n2]);
      }
    float zp = 0.f, zq = 0.f;
#pragma unroll
    for (int kb = 0; kb < 2; ++kb) {
      const float* hvp = hvf + vb64 + kb * 32 + quad * 8;
      const float* hvq = hvb + vb64 + kb * 32 + quad * 8;
#pragma unroll
      for (int jj = 0; jj < 8; ++jj) {
        float qv = (float)qa[kb][jj];
        zp += qv * hvp[jj];
        zq += qv * hvq[jj];
      }
    }
    zp += __shfl_xor(zp, 16); zp += __shfl_xor(zp, 32);
    zq += __shfl_xor(zq, 16); zq += __shfl_xor(zq, 32);
#pragma unroll
    for (int n2 = 0; n2 < 4; ++n2)
#pragma unroll
      for (int r = 0; r < 4; ++r)
        oacc[n2][r] += rowp[r] * pacc[n2][r] + rown[r] * qacc[n2][r];
#pragma unroll
    for (int r = 0; r < 4; ++r)
      zstate[r] = rowp[r] * __shfl(zp, quad * 4 + r) + rown[r] * __shfl(zq, quad * 4 + r);
  }

  float rz[4];
#pragma unroll
  for (int r = 0; r < 4; ++r) {
    float z = zdiag[r];
    z += __shfl_xor(z, 1);
    z += __shfl_xor(z, 2);
    z += __shfl_xor(z, 4);
    z += __shfl_xor(z, 8);
    z += zstate[r];
    rz[r] = 1.f / fmaxf(z, 1e-6f);
  }

#pragma unroll
  for (int n2 = 0; n2 < 4; ++n2)
#pragma unroll
    for (int r = 0; r < 4; ++r) {
      int i = i0 + wid * 16 + quad * 4 + r;
      int col = h * 64 + n2 * 16 + ln;
      attn_out[(size_t)(b * TT + i) * DD + col] = f2bf(oacc[n2][r] * rz[r]);
    }
}

extern "C" void kernel_launch(void* const* d_in, const int* in_sizes, int n_in,
                              void* d_out, int out_size, void* d_ws, size_t ws_size,
                              hipStream_t stream) {
  const float* x = (const float*)d_in[0];
  const unsigned char* msk = (const unsigned char*)d_in[1];
  const float* wq = (const float*)d_in[2];
  const float* wk = (const float*)d_in[3];
  const float* wv = (const float*)d_in[4];
  const float* wo = (const float*)d_in[5];
  const float* bo = (const float*)d_in[6];
  const float* g1 = (const float*)d_in[7];
  const float* b1 = (const float*)d_in[8];
  const float* g2 = (const float*)d_in[9];
  const float* b2 = (const float*)d_in[10];
  const float* w1 = (const float*)d_in[11];
  const float* bf1 = (const float*)d_in[12];
  const float* w2 = (const float*)d_in[13];
  const float* bf2 = (const float*)d_in[14];
  const float* dlg = (const float*)d_in[15];
  float* out = (float*)d_out;

  char* p = (char*)d_ws;
  size_t off = 0;
  auto carve = [&](size_t bytes) {
    char* q = p + off;
    off += (bytes + 255) & ~(size_t)255;
    return q;
  };
  unsigned short* xn = (unsigned short*)carve((size_t)M4 * DD * 2);
  unsigned short* wqkvT = (unsigned short*)carve((size_t)1536 * DD * 2);
  unsigned short* woT = (unsigned short*)carve((size_t)DD * DD * 2);
  unsigned short* w1T = (unsigned short*)carve((size_t)FF_ * DD * 2);
  unsigned short* w2T = (unsigned short*)carve((size_t)DD * FF_ * 2);
  unsigned short* Qb = (unsigned short*)carve((size_t)16 * TT * HD * 2);
  unsigned short* Kb = (unsigned short*)carve((size_t)16 * TT * HD * 2);
  unsigned short* Ktb = (unsigned short*)carve((size_t)16 * HD * TT * 2);
  unsigned short* Vtb = (unsigned short*)carve((size_t)16 * HD * TT * 2);
  unsigned short* attn = (unsigned short*)carve((size_t)M4 * DD * 2);
  float* x2 = (float*)carve((size_t)M4 * DD * 4);
  unsigned short* xn2 = (unsigned short*)carve((size_t)M4 * DD * 2);
  unsigned short* ffh = (unsigned short*)carve((size_t)M4 * FF_ * 2);
  unsigned short* FTfb = (unsigned short*)carve((size_t)16 * NC * 4096 * 2);
  unsigned short* FTbb = (unsigned short*)carve((size_t)16 * NC * 4096 * 2);
  unsigned short* HTfb = (unsigned short*)carve((size_t)16 * NC * 4096 * 2);
  unsigned short* HTbb = (unsigned short*)carve((size_t)16 * NC * 4096 * 2);
  float* fvecb = (float*)carve((size_t)16 * NC * 64 * 4);
  float* bvecb = (float*)carve((size_t)16 * NC * 64 * 4);
  float* hvfb = (float*)carve((size_t)16 * NC * 64 * 4);
  float* hvbb = (float*)carve((size_t)16 * NC * 64 * 4);

  prep_kernel<<<5120, 256, 0, stream>>>(wq, wk, wv, wo, w1, w2,
                                        wqkvT, woT, w1T, w2T, x, g1, b1, xn);

  // QKV: 64x128, KU=4 (48KB), 768 blocks (3/CU); coalesced transposed epilogue
  gemm_ku<64, 128, 4, 512, 0, 3><<<dim3(M4 / 64, 1536 / 128), 256, 0, stream>>>(
      xn, wqkvT, 1536, nullptr, nullptr, nullptr, Qb, Kb, Vtb, Ktb, msk);

  state_build<<<dim3(NC, 16), 256, 0, stream>>>(Ktb, Vtb, dlg, FTfb, FTbb, fvecb, bvecb);
  state_combine<<<dim3(NC, 16), 256, 0, stream>>>(FTfb, FTbb, fvecb, bvecb, dlg,
                                                  HTfb, HTbb, hvfb, hvbb);
  attn_kernel<<<dim3(NC, 16), 256, 0, stream>>>(Qb, Kb, Vtb, dlg, HTfb, HTbb,
                                                hvfb, hvbb, attn);

  // out-proj: 64x64, KU=4 (32KB -> 4+/CU), 512 blocks
  gemm_ku<64, 64, 4, 512, 1, 4><<<dim3(M4 / 64, DD / 64), 256, 0, stream>>>(
      attn, woT, DD, bo, x, x2, nullptr, nullptr, nullptr, nullptr, nullptr);

  ln_kernel<<<M4, 128, 0, stream>>>(x2, g2, b2, xn2);

  // FFN1: 64x128, KU=4, 1024 blocks
  gemm_ku<64, 128, 4, 512, 2, 3><<<dim3(M4 / 64, FF_ / 128), 256, 0, stream>>>(
      xn2, w1T, FF_, bf1, nullptr, nullptr, ffh, nullptr, nullptr, nullptr, nullptr);

  // FFN2: 64x64, KU=4 (32KB), 512 blocks
  gemm_ku<64, 64, 4, 2048, 1, 4><<<dim3(M4 / 64, DD / 64), 256, 0, stream>>>(
      ffh, w2T, DD, bf2, x2, out, nullptr, nullptr, nullptr, nullptr, nullptr);
}